// Round 5
// baseline (221.520 us; speedup 1.0000x reference)
//
#include <hip/hip_runtime.h>

#define HW 4096
#define NC 96
#define NB 4
#define MID 24
#define NOUT 256
#define BEPS 1e-5f
#define SCALE_E 0.10206207261596575f  // 1/sqrt(96)

typedef unsigned short u16;
typedef short bf16x8 __attribute__((ext_vector_type(8)));
typedef unsigned short u16x8 __attribute__((ext_vector_type(8)));
typedef float f32x16 __attribute__((ext_vector_type(16)));

__device__ __forceinline__ u16 bfh(float x) {
  unsigned u = __float_as_uint(x);
  return (u16)((u + 0x7FFFu + ((u >> 16) & 1u)) >> 16);  // RNE bf16
}
__device__ __forceinline__ float bf2f(u16 h) {
  return __uint_as_float(((unsigned)h) << 16);
}

// ---------------------------------------------------------------------------
// Prep: pr = Wr*rgb, pd = Wd*dep; psum = pr+pd fp32 [b][c][n]; transposed
// hi/lo bf16 rows prT2/pdT2[b][n][192] = [hi 96 | lo 96].
// ---------------------------------------------------------------------------
__launch_bounds__(256)
__global__ void k_prep(const float* __restrict__ rgb, const float* __restrict__ dep,
                       const float* __restrict__ Wr, const float* __restrict__ Wd,
                       float* __restrict__ psum, u16* __restrict__ prT2, u16* __restrict__ pdT2) {
  __shared__ u16 buf[2][64][48];   // [arr][n-local][hi24|lo24] for this quarter
  const int tid = threadIdx.x;
  const int slot = tid & 31;                                   // n-pair slot
  const int og = __builtin_amdgcn_readfirstlane(tid >> 6);     // wave-uniform o-group
  const int b = blockIdx.y, q = blockIdx.z;
  const int n0 = blockIdx.x * 64;
  const int obase = q * 24 + og * 6;

  float ar[6][2], ad[6][2];
  #pragma unroll
  for (int o = 0; o < 6; ++o) { ar[o][0] = ar[o][1] = ad[o][0] = ad[o][1] = 0.f; }

  const float* rb = rgb + (size_t)b * NC * HW + n0;
  const float* db = dep + (size_t)b * NC * HW + n0;
  #pragma unroll 4
  for (int c = 0; c < NC; ++c) {
    float2 xr = ((const float2*)(rb + (size_t)c * HW))[slot];
    float2 xd = ((const float2*)(db + (size_t)c * HW))[slot];
    #pragma unroll
    for (int o = 0; o < 6; ++o) {
      float wr = Wr[(obase + o) * NC + c];   // uniform -> s_load
      float wd = Wd[(obase + o) * NC + c];
      ar[o][0] = fmaf(wr, xr.x, ar[o][0]);
      ar[o][1] = fmaf(wr, xr.y, ar[o][1]);
      ad[o][0] = fmaf(wd, xd.x, ad[o][0]);
      ad[o][1] = fmaf(wd, xd.y, ad[o][1]);
    }
  }

  #pragma unroll
  for (int o = 0; o < 6; ++o) {
    float2 ps = make_float2(ar[o][0] + ad[o][0], ar[o][1] + ad[o][1]);
    *(float2*)&psum[((size_t)b * NC + obase + o) * HW + n0 + slot * 2] = ps;
    #pragma unroll
    for (int j = 0; j < 2; ++j) {
      int nl = slot * 2 + j;
      int ol = og * 6 + o;
      u16 h = bfh(ar[o][j]);
      buf[0][nl][ol] = h;
      buf[0][nl][24 + ol] = bfh(ar[o][j] - bf2f(h));
      u16 h2 = bfh(ad[o][j]);
      buf[1][nl][ol] = h2;
      buf[1][nl][24 + ol] = bfh(ad[o][j] - bf2f(h2));
    }
  }
  __syncthreads();

  for (int ch = tid; ch < 768; ch += 256) {
    int arr = ch / 384;
    int r = ch % 384;
    int nl = r / 6, piece = r % 6;
    u16* dst = (arr ? pdT2 : prT2) + ((size_t)b * HW + n0 + nl) * 192 + q * 24;
    u16x8 v;
    if (piece < 3) {
      v = *(const u16x8*)&buf[arr][nl][piece * 8];
      *(u16x8*)&dst[piece * 8] = v;
    } else {
      v = *(const u16x8*)&buf[arr][nl][24 + (piece - 3) * 8];
      *(u16x8*)&dst[96 + (piece - 3) * 8] = v;
    }
  }
}

// ---------------------------------------------------------------------------
// MFMA energy pass, double-buffered 16-ch steps (T3-min 2-phase).
// Block tile: 128 A-rows x 256 B-cols, 4 waves (2x2), wave tile 64x128.
// LDS row = 64B = 4 slots of 16B: logical {0,1}=hi ch[k0..k0+16), {2,3}=lo.
// phys slot = logical ^ ((row>>1)&3). 2 buffers: 24KB each -> 50KB total,
// 3 blocks/CU. Loop: STAGE(next) -> compute(cur) -> barrier.
// PASS 0: A=pr(n) B=pd(m): colsum over n of exp(e*s)          -> zpart
// PASS 1: A=pd(m) B=pr(n): colsum over m of exp(e*s - lnZ[m]) -> spart
// ---------------------------------------------------------------------------
template <int PASS>
__launch_bounds__(256, 3)
__global__ void k_energy(const u16* __restrict__ At, const u16* __restrict__ Bt,
                         const float* __restrict__ nlz, float* __restrict__ part) {
  __shared__ u16 sA[2][128 * 32];   // 8KB per buffer
  __shared__ u16 sB[2][256 * 32];   // 16KB per buffer
  __shared__ float red[2][256];
  const int tid = threadIdx.x;
  const int lane = tid & 63, wid = tid >> 6;
  const int wA = wid >> 1, wB = wid & 1;
  const int b = blockIdx.z;
  const int a0 = blockIdx.y * 128;
  const int c0 = blockIdx.x * 256;
  const u16* Ab = At + ((size_t)b * HW + a0) * 192;
  const u16* Bb = Bt + ((size_t)b * HW + c0) * 192;

  f32x16 acc[2][4];
  #pragma unroll
  for (int ta = 0; ta < 2; ++ta)
    #pragma unroll
    for (int tb = 0; tb < 4; ++tb)
      #pragma unroll
      for (int q = 0; q < 16; ++q) acc[ta][tb][q] = 0.f;

  // stage one 16-ch step into buffer `bf`
  auto stage = [&](int bf, int step) {
    const int k0 = step * 16;
    #pragma unroll
    for (int i = 0; i < 2; ++i) {
      int idx = i * 256 + tid;
      int r = idx >> 2, s = idx & 3;
      int g = s ^ ((r >> 1) & 3);
      int soff = (g >> 1) * 96 + k0 + (g & 1) * 8;
      __builtin_amdgcn_global_load_lds(Ab + (size_t)r * 192 + soff, &sA[bf][idx * 8], 16, 0, 0);
    }
    #pragma unroll
    for (int i = 0; i < 4; ++i) {
      int idx = i * 256 + tid;
      int r = idx >> 2, s = idx & 3;
      int g = s ^ ((r >> 1) & 3);
      int soff = (g >> 1) * 96 + k0 + (g & 1) * 8;
      __builtin_amdgcn_global_load_lds(Bb + (size_t)r * 192 + soff, &sB[bf][idx * 8], 16, 0, 0);
    }
  };

  auto compute = [&](int bf) {
    const int gh = lane >> 5;
    bf16x8 ah[2], al[2];
    #pragma unroll
    for (int ta = 0; ta < 2; ++ta) {
      int r = wA * 64 + ta * 32 + (lane & 31);
      int swz = (r >> 1) & 3;
      ah[ta] = *(const bf16x8*)&sA[bf][r * 32 + (gh ^ swz) * 8];
      al[ta] = *(const bf16x8*)&sA[bf][r * 32 + ((gh + 2) ^ swz) * 8];
    }
    #pragma unroll
    for (int tb = 0; tb < 4; ++tb) {
      int r = wB * 128 + tb * 32 + (lane & 31);
      int swz = (r >> 1) & 3;
      bf16x8 bh = *(const bf16x8*)&sB[bf][r * 32 + (gh ^ swz) * 8];
      bf16x8 bl = *(const bf16x8*)&sB[bf][r * 32 + ((gh + 2) ^ swz) * 8];
      #pragma unroll
      for (int ta = 0; ta < 2; ++ta) {
        acc[ta][tb] = __builtin_amdgcn_mfma_f32_32x32x16_bf16(ah[ta], bh, acc[ta][tb], 0, 0, 0);
        acc[ta][tb] = __builtin_amdgcn_mfma_f32_32x32x16_bf16(al[ta], bh, acc[ta][tb], 0, 0, 0);
        acc[ta][tb] = __builtin_amdgcn_mfma_f32_32x32x16_bf16(ah[ta], bl, acc[ta][tb], 0, 0, 0);
      }
    }
  };

  stage(0, 0);
  __syncthreads();
  int cur = 0;
  #pragma unroll
  for (int step = 0; step < 5; ++step) {
    stage(cur ^ 1, step + 1);   // issue next-step loads (async, in flight)
    compute(cur);               // MFMA on current buffer hides stage latency
    __syncthreads();            // drains vmcnt -> next buffer ready
    cur ^= 1;
  }
  compute(cur);

  // exp + column sums (over A-rows). C/D: col=lane&31, row=(q&3)+8*(q>>2)+4*(lane>>5)
  float csum[4] = {0.f, 0.f, 0.f, 0.f};
  float nlzv = 0.f;
  if (PASS) nlzv = nlz[(size_t)b * HW + a0 + wA * 64 + lane];
  #pragma unroll
  for (int ta = 0; ta < 2; ++ta) {
    #pragma unroll
    for (int q = 0; q < 16; ++q) {
      float bias = 0.f;
      if (PASS) {
        int src = ta * 32 + (q & 3) + 8 * (q >> 2) + 4 * (lane >> 5);
        bias = __shfl(nlzv, src, 64);
      }
      #pragma unroll
      for (int tb = 0; tb < 4; ++tb)
        csum[tb] += __expf(fmaf(acc[ta][tb][q], SCALE_E, bias));
    }
  }
  #pragma unroll
  for (int tb = 0; tb < 4; ++tb) csum[tb] += __shfl_xor(csum[tb], 32, 64);
  __syncthreads();   // red[] reuse barrier (stage loop done)
  if (lane < 32) {
    #pragma unroll
    for (int tb = 0; tb < 4; ++tb) red[wA][wB * 128 + tb * 32 + lane] = csum[tb];
  }
  __syncthreads();
  part[((size_t)blockIdx.y * NB + b) * HW + c0 + tid] = red[0][tid] + red[1][tid];
}

// ---------------------------------------------------------------------------
__global__ void k_zred(const float* __restrict__ zpart, float* __restrict__ nlz) {
  int idx = blockIdx.x * 256 + threadIdx.x;  // over NB*HW
  float s = 0.f;
  #pragma unroll
  for (int t = 0; t < 32; ++t) s += zpart[(size_t)t * (NB * HW) + idx];
  nlz[idx] = -logf(s);
}

__global__ void k_sred(const float* __restrict__ spart, float* __restrict__ sv) {
  int idx = blockIdx.x * 256 + threadIdx.x;
  float a = 0.f;
  #pragma unroll
  for (int t = 0; t < 32; ++t) a += spart[(size_t)t * (NB * HW) + idx];
  sv[idx] = a;
}

// ---------------------------------------------------------------------------
// gap[b,c] = (1/HW)*[ sum_n psum[c,n]*s[n] + sum_n (rgb+dep)[c,n] ]
// ---------------------------------------------------------------------------
__launch_bounds__(256)
__global__ void k_gap(const float* __restrict__ psum, const float* __restrict__ rgb,
                      const float* __restrict__ dep, const float* __restrict__ sv,
                      float* __restrict__ gap) {
  const int c = blockIdx.x, b = blockIdx.y;
  const size_t off = ((size_t)b * NC + c) * HW;
  const float* pp = psum + off;
  const float* rp = rgb + off;
  const float* dp = dep + off;
  const float* sp = sv + (size_t)b * HW;
  float a1 = 0.f, a2 = 0.f;
  for (int n = threadIdx.x * 4; n < HW; n += 1024) {
    float4 p = *(const float4*)&pp[n];
    float4 s4 = *(const float4*)&sp[n];
    float4 r4 = *(const float4*)&rp[n];
    float4 d4 = *(const float4*)&dp[n];
    a1 += p.x * s4.x + p.y * s4.y + p.z * s4.z + p.w * s4.w;
    a2 += (r4.x + d4.x) + (r4.y + d4.y) + (r4.z + d4.z) + (r4.w + d4.w);
  }
  #pragma unroll
  for (int o = 32; o > 0; o >>= 1) {
    a1 += __shfl_down(a1, o, 64);
    a2 += __shfl_down(a2, o, 64);
  }
  __shared__ float r1[4], r2[4];
  const int wv = threadIdx.x >> 6;
  if ((threadIdx.x & 63) == 0) { r1[wv] = a1; r2[wv] = a2; }
  __syncthreads();
  if (threadIdx.x == 0) {
    float t1 = r1[0] + r1[1] + r1[2] + r1[3];
    float t2 = r2[0] + r2[1] + r2[2] + r2[3];
    gap[b * NC + c] = (t1 + t2) * (1.0f / HW);
  }
}

// ---------------------------------------------------------------------------
// Tiny MLP + training-mode BatchNorm (over batch of 4) + ReLU, one block.
// ---------------------------------------------------------------------------
__launch_bounds__(256)
__global__ void k_mlp(const float* __restrict__ gap,
                      const float* __restrict__ Wm1, const float* __restrict__ g1,
                      const float* __restrict__ b1,
                      const float* __restrict__ Wm2, const float* __restrict__ g2,
                      const float* __restrict__ b2, float* __restrict__ out) {
  __shared__ float gl[NB * NC];
  __shared__ float h[NB * MID];
  __shared__ float h1r[NB * MID];
  __shared__ float h2[NB * NOUT];
  const int tid = threadIdx.x;
  for (int i = tid; i < NB * NC; i += 256) gl[i] = gap[i];
  __syncthreads();

  if (tid < NB * MID) {
    int b = tid / MID, j = tid % MID;
    float acc = 0.f;
    #pragma unroll
    for (int c = 0; c < NC; ++c) acc += gl[b * NC + c] * Wm1[j * NC + c];
    h[b * MID + j] = acc;
  }
  __syncthreads();

  if (tid < MID) {
    float x0 = h[0 * MID + tid], x1 = h[1 * MID + tid];
    float x2 = h[2 * MID + tid], x3 = h[3 * MID + tid];
    float mu = 0.25f * (x0 + x1 + x2 + x3);
    float d0 = x0 - mu, d1 = x1 - mu, d2 = x2 - mu, d3 = x3 - mu;
    float v = 0.25f * (d0 * d0 + d1 * d1 + d2 * d2 + d3 * d3);
    float sc = g1[tid] * rsqrtf(v + BEPS);
    float bb = b1[tid];
    h1r[0 * MID + tid] = fmaxf(d0 * sc + bb, 0.f);
    h1r[1 * MID + tid] = fmaxf(d1 * sc + bb, 0.f);
    h1r[2 * MID + tid] = fmaxf(d2 * sc + bb, 0.f);
    h1r[3 * MID + tid] = fmaxf(d3 * sc + bb, 0.f);
  }
  __syncthreads();

  for (int idx = tid; idx < NB * NOUT; idx += 256) {
    int b = idx >> 8, o = idx & 255;
    float acc = 0.f;
    #pragma unroll
    for (int j = 0; j < MID; ++j) acc += h1r[b * MID + j] * Wm2[o * MID + j];
    h2[b * NOUT + o] = acc;
  }
  __syncthreads();

  if (tid < NOUT) {
    float x0 = h2[0 * NOUT + tid], x1 = h2[1 * NOUT + tid];
    float x2 = h2[2 * NOUT + tid], x3 = h2[3 * NOUT + tid];
    float mu = 0.25f * (x0 + x1 + x2 + x3);
    float d0 = x0 - mu, d1 = x1 - mu, d2 = x2 - mu, d3 = x3 - mu;
    float v = 0.25f * (d0 * d0 + d1 * d1 + d2 * d2 + d3 * d3);
    float sc = g2[tid] * rsqrtf(v + BEPS);
    float bb = b2[tid];
    out[0 * NOUT + tid] = fmaxf(d0 * sc + bb, 0.f);
    out[1 * NOUT + tid] = fmaxf(d1 * sc + bb, 0.f);
    out[2 * NOUT + tid] = fmaxf(d2 * sc + bb, 0.f);
    out[3 * NOUT + tid] = fmaxf(d3 * sc + bb, 0.f);
  }
}

// ---------------------------------------------------------------------------
extern "C" void kernel_launch(void* const* d_in, const int* in_sizes, int n_in,
                              void* d_out, int out_size, void* d_ws, size_t ws_size,
                              hipStream_t stream) {
  const float* rgb   = (const float*)d_in[0];
  const float* dep   = (const float*)d_in[1];
  const float* Wd    = (const float*)d_in[2];
  const float* Wr    = (const float*)d_in[3];
  const float* Wm1   = (const float*)d_in[4];
  const float* bn1_g = (const float*)d_in[5];
  const float* bn1_b = (const float*)d_in[6];
  const float* Wm2   = (const float*)d_in[7];
  const float* bn2_g = (const float*)d_in[8];
  const float* bn2_b = (const float*)d_in[9];
  float* out = (float*)d_out;

  char* w = (char*)d_ws;
  u16* prT2 = (u16*)w;            w += (size_t)NB * HW * 192 * 2;   // 6.3 MB
  u16* pdT2 = (u16*)w;            w += (size_t)NB * HW * 192 * 2;   // 6.3 MB
  float* psum  = (float*)w;       w += (size_t)NB * NC * HW * 4;    // 6.3 MB
  float* zpart = (float*)w;       w += (size_t)32 * NB * HW * 4;    // 2 MB
  float* nlz   = (float*)w;       w += (size_t)NB * HW * 4;
  float* spart = (float*)w;       w += (size_t)32 * NB * HW * 4;    // 2 MB
  float* sv    = (float*)w;       w += (size_t)NB * HW * 4;
  float* gap   = (float*)w;       w += (size_t)NB * NC * 4;

  k_prep<<<dim3(HW / 64, NB, 4), 256, 0, stream>>>(rgb, dep, Wr, Wd, psum, prT2, pdT2);
  k_energy<0><<<dim3(HW / 256, HW / 128, NB), 256, 0, stream>>>(prT2, pdT2, nullptr, zpart);
  k_zred<<<NB * HW / 256, 256, 0, stream>>>(zpart, nlz);
  k_energy<1><<<dim3(HW / 256, HW / 128, NB), 256, 0, stream>>>(pdT2, prT2, nlz, spart);
  k_sred<<<NB * HW / 256, 256, 0, stream>>>(spart, sv);
  k_gap<<<dim3(NC, NB), 256, 0, stream>>>(psum, rgb, dep, sv, gap);
  k_mlp<<<1, 256, 0, stream>>>(gap, Wm1, bn1_g, bn1_b, Wm2, bn2_g, bn2_b, out);
}

// Round 6
// 151.601 us; speedup vs baseline: 1.4612x; 1.4612x over previous
//
#include <hip/hip_runtime.h>

#define HW 4096
#define NC 96
#define NB 4
#define MID 24
#define NOUT 256
#define BEPS 1e-5f
#define SCALE_E 0.10206207261596575f  // 1/sqrt(96)

typedef unsigned short u16;
typedef short bf16x8 __attribute__((ext_vector_type(8)));
typedef unsigned short u16x8 __attribute__((ext_vector_type(8)));
typedef float f32x16 __attribute__((ext_vector_type(16)));

__device__ __forceinline__ u16 bfh(float x) {
  unsigned u = __float_as_uint(x);
  return (u16)((u + 0x7FFFu + ((u >> 16) & 1u)) >> 16);  // RNE bf16
}
__device__ __forceinline__ float bf2f(u16 h) {
  return __uint_as_float(((unsigned)h) << 16);
}

// ---------------------------------------------------------------------------
// Prep: pr = Wr*rgb, pd = Wd*dep; psum = pr+pd fp32 [b][c][n]; transposed
// hi/lo bf16 rows prT2/pdT2[b][n][192] = [hi 96 | lo 96].
// ---------------------------------------------------------------------------
__launch_bounds__(256)
__global__ void k_prep(const float* __restrict__ rgb, const float* __restrict__ dep,
                       const float* __restrict__ Wr, const float* __restrict__ Wd,
                       float* __restrict__ psum, u16* __restrict__ prT2, u16* __restrict__ pdT2) {
  __shared__ u16 buf[2][64][48];   // [arr][n-local][hi24|lo24] for this quarter
  const int tid = threadIdx.x;
  const int slot = tid & 31;                                   // n-pair slot
  const int og = __builtin_amdgcn_readfirstlane(tid >> 6);     // wave-uniform o-group
  const int b = blockIdx.y, q = blockIdx.z;
  const int n0 = blockIdx.x * 64;
  const int obase = q * 24 + og * 6;

  float ar[6][2], ad[6][2];
  #pragma unroll
  for (int o = 0; o < 6; ++o) { ar[o][0] = ar[o][1] = ad[o][0] = ad[o][1] = 0.f; }

  const float* rb = rgb + (size_t)b * NC * HW + n0;
  const float* db = dep + (size_t)b * NC * HW + n0;
  #pragma unroll 4
  for (int c = 0; c < NC; ++c) {
    float2 xr = ((const float2*)(rb + (size_t)c * HW))[slot];
    float2 xd = ((const float2*)(db + (size_t)c * HW))[slot];
    #pragma unroll
    for (int o = 0; o < 6; ++o) {
      float wr = Wr[(obase + o) * NC + c];   // uniform -> s_load
      float wd = Wd[(obase + o) * NC + c];
      ar[o][0] = fmaf(wr, xr.x, ar[o][0]);
      ar[o][1] = fmaf(wr, xr.y, ar[o][1]);
      ad[o][0] = fmaf(wd, xd.x, ad[o][0]);
      ad[o][1] = fmaf(wd, xd.y, ad[o][1]);
    }
  }

  #pragma unroll
  for (int o = 0; o < 6; ++o) {
    float2 ps = make_float2(ar[o][0] + ad[o][0], ar[o][1] + ad[o][1]);
    *(float2*)&psum[((size_t)b * NC + obase + o) * HW + n0 + slot * 2] = ps;
    #pragma unroll
    for (int j = 0; j < 2; ++j) {
      int nl = slot * 2 + j;
      int ol = og * 6 + o;
      u16 h = bfh(ar[o][j]);
      buf[0][nl][ol] = h;
      buf[0][nl][24 + ol] = bfh(ar[o][j] - bf2f(h));
      u16 h2 = bfh(ad[o][j]);
      buf[1][nl][ol] = h2;
      buf[1][nl][24 + ol] = bfh(ad[o][j] - bf2f(h2));
    }
  }
  __syncthreads();

  for (int ch = tid; ch < 768; ch += 256) {
    int arr = ch / 384;
    int r = ch % 384;
    int nl = r / 6, piece = r % 6;
    u16* dst = (arr ? pdT2 : prT2) + ((size_t)b * HW + n0 + nl) * 192 + q * 24;
    u16x8 v;
    if (piece < 3) {
      v = *(const u16x8*)&buf[arr][nl][piece * 8];
      *(u16x8*)&dst[piece * 8] = v;
    } else {
      v = *(const u16x8*)&buf[arr][nl][24 + (piece - 3) * 8];
      *(u16x8*)&dst[96 + (piece - 3) * 8] = v;
    }
  }
}

// ---------------------------------------------------------------------------
// MFMA energy pass, double-buffered 16-ch steps (T3-min 2-phase).
// Block tile: 128 A-rows x 256 B-cols, 4 waves (2x2), wave tile 64x128.
// LDS row = 64B = 4 slots of 16B: logical {0,1}=hi ch[k0..k0+16), {2,3}=lo.
// phys slot = logical ^ ((row>>1)&3). 2 buffers: 24KB each -> 50KB total.
// launch_bounds(256,2): acc[2][4] f32x16 = 128 VGPR must NOT spill
// (round-5 lesson: (256,3) clamped to 84 VGPR -> 297MB scratch traffic).
// Loop: STAGE(next) -> compute(cur) -> barrier.
// PASS 0: A=pr(n) B=pd(m): colsum over n of exp(e*s)          -> zpart
// PASS 1: A=pd(m) B=pr(n): colsum over m of exp(e*s - lnZ[m]) -> spart
// ---------------------------------------------------------------------------
template <int PASS>
__launch_bounds__(256, 2)
__global__ void k_energy(const u16* __restrict__ At, const u16* __restrict__ Bt,
                         const float* __restrict__ nlz, float* __restrict__ part) {
  __shared__ u16 sA[2][128 * 32];   // 8KB per buffer
  __shared__ u16 sB[2][256 * 32];   // 16KB per buffer
  __shared__ float red[2][256];
  const int tid = threadIdx.x;
  const int lane = tid & 63, wid = tid >> 6;
  const int wA = wid >> 1, wB = wid & 1;
  const int b = blockIdx.z;
  const int a0 = blockIdx.y * 128;
  const int c0 = blockIdx.x * 256;
  const u16* Ab = At + ((size_t)b * HW + a0) * 192;
  const u16* Bb = Bt + ((size_t)b * HW + c0) * 192;

  f32x16 acc[2][4];
  #pragma unroll
  for (int ta = 0; ta < 2; ++ta)
    #pragma unroll
    for (int tb = 0; tb < 4; ++tb)
      #pragma unroll
      for (int q = 0; q < 16; ++q) acc[ta][tb][q] = 0.f;

  // stage one 16-ch step into buffer `bf`
  auto stage = [&](int bf, int step) {
    const int k0 = step * 16;
    #pragma unroll
    for (int i = 0; i < 2; ++i) {
      int idx = i * 256 + tid;
      int r = idx >> 2, s = idx & 3;
      int g = s ^ ((r >> 1) & 3);
      int soff = (g >> 1) * 96 + k0 + (g & 1) * 8;
      __builtin_amdgcn_global_load_lds(Ab + (size_t)r * 192 + soff, &sA[bf][idx * 8], 16, 0, 0);
    }
    #pragma unroll
    for (int i = 0; i < 4; ++i) {
      int idx = i * 256 + tid;
      int r = idx >> 2, s = idx & 3;
      int g = s ^ ((r >> 1) & 3);
      int soff = (g >> 1) * 96 + k0 + (g & 1) * 8;
      __builtin_amdgcn_global_load_lds(Bb + (size_t)r * 192 + soff, &sB[bf][idx * 8], 16, 0, 0);
    }
  };

  auto compute = [&](int bf) {
    const int gh = lane >> 5;
    bf16x8 ah[2], al[2];
    #pragma unroll
    for (int ta = 0; ta < 2; ++ta) {
      int r = wA * 64 + ta * 32 + (lane & 31);
      int swz = (r >> 1) & 3;
      ah[ta] = *(const bf16x8*)&sA[bf][r * 32 + (gh ^ swz) * 8];
      al[ta] = *(const bf16x8*)&sA[bf][r * 32 + ((gh + 2) ^ swz) * 8];
    }
    #pragma unroll
    for (int tb = 0; tb < 4; ++tb) {
      int r = wB * 128 + tb * 32 + (lane & 31);
      int swz = (r >> 1) & 3;
      bf16x8 bh = *(const bf16x8*)&sB[bf][r * 32 + (gh ^ swz) * 8];
      bf16x8 bl = *(const bf16x8*)&sB[bf][r * 32 + ((gh + 2) ^ swz) * 8];
      #pragma unroll
      for (int ta = 0; ta < 2; ++ta) {
        acc[ta][tb] = __builtin_amdgcn_mfma_f32_32x32x16_bf16(ah[ta], bh, acc[ta][tb], 0, 0, 0);
        acc[ta][tb] = __builtin_amdgcn_mfma_f32_32x32x16_bf16(al[ta], bh, acc[ta][tb], 0, 0, 0);
        acc[ta][tb] = __builtin_amdgcn_mfma_f32_32x32x16_bf16(ah[ta], bl, acc[ta][tb], 0, 0, 0);
      }
    }
  };

  stage(0, 0);
  __syncthreads();
  int cur = 0;
  #pragma unroll
  for (int step = 0; step < 5; ++step) {
    stage(cur ^ 1, step + 1);   // issue next-step loads (async, in flight)
    compute(cur);               // MFMA on current buffer hides stage latency
    __syncthreads();            // drains vmcnt -> next buffer ready
    cur ^= 1;
  }
  compute(cur);

  // exp + column sums (over A-rows). C/D: col=lane&31, row=(q&3)+8*(q>>2)+4*(lane>>5)
  float csum[4] = {0.f, 0.f, 0.f, 0.f};
  float nlzv = 0.f;
  if (PASS) nlzv = nlz[(size_t)b * HW + a0 + wA * 64 + lane];
  #pragma unroll
  for (int ta = 0; ta < 2; ++ta) {
    #pragma unroll
    for (int q = 0; q < 16; ++q) {
      float bias = 0.f;
      if (PASS) {
        int src = ta * 32 + (q & 3) + 8 * (q >> 2) + 4 * (lane >> 5);
        bias = __shfl(nlzv, src, 64);
      }
      #pragma unroll
      for (int tb = 0; tb < 4; ++tb)
        csum[tb] += __expf(fmaf(acc[ta][tb][q], SCALE_E, bias));
    }
  }
  #pragma unroll
  for (int tb = 0; tb < 4; ++tb) csum[tb] += __shfl_xor(csum[tb], 32, 64);
  __syncthreads();   // red[] reuse barrier (stage loop done)
  if (lane < 32) {
    #pragma unroll
    for (int tb = 0; tb < 4; ++tb) red[wA][wB * 128 + tb * 32 + lane] = csum[tb];
  }
  __syncthreads();
  part[((size_t)blockIdx.y * NB + b) * HW + c0 + tid] = red[0][tid] + red[1][tid];
}

// ---------------------------------------------------------------------------
__global__ void k_zred(const float* __restrict__ zpart, float* __restrict__ nlz) {
  int idx = blockIdx.x * 256 + threadIdx.x;  // over NB*HW
  float s = 0.f;
  #pragma unroll
  for (int t = 0; t < 32; ++t) s += zpart[(size_t)t * (NB * HW) + idx];
  nlz[idx] = -logf(s);
}

__global__ void k_sred(const float* __restrict__ spart, float* __restrict__ sv) {
  int idx = blockIdx.x * 256 + threadIdx.x;
  float a = 0.f;
  #pragma unroll
  for (int t = 0; t < 32; ++t) a += spart[(size_t)t * (NB * HW) + idx];
  sv[idx] = a;
}

// ---------------------------------------------------------------------------
// gap[b,c] = (1/HW)*[ sum_n psum[c,n]*s[n] + sum_n (rgb+dep)[c,n] ]
// ---------------------------------------------------------------------------
__launch_bounds__(256)
__global__ void k_gap(const float* __restrict__ psum, const float* __restrict__ rgb,
                      const float* __restrict__ dep, const float* __restrict__ sv,
                      float* __restrict__ gap) {
  const int c = blockIdx.x, b = blockIdx.y;
  const size_t off = ((size_t)b * NC + c) * HW;
  const float* pp = psum + off;
  const float* rp = rgb + off;
  const float* dp = dep + off;
  const float* sp = sv + (size_t)b * HW;
  float a1 = 0.f, a2 = 0.f;
  for (int n = threadIdx.x * 4; n < HW; n += 1024) {
    float4 p = *(const float4*)&pp[n];
    float4 s4 = *(const float4*)&sp[n];
    float4 r4 = *(const float4*)&rp[n];
    float4 d4 = *(const float4*)&dp[n];
    a1 += p.x * s4.x + p.y * s4.y + p.z * s4.z + p.w * s4.w;
    a2 += (r4.x + d4.x) + (r4.y + d4.y) + (r4.z + d4.z) + (r4.w + d4.w);
  }
  #pragma unroll
  for (int o = 32; o > 0; o >>= 1) {
    a1 += __shfl_down(a1, o, 64);
    a2 += __shfl_down(a2, o, 64);
  }
  __shared__ float r1[4], r2[4];
  const int wv = threadIdx.x >> 6;
  if ((threadIdx.x & 63) == 0) { r1[wv] = a1; r2[wv] = a2; }
  __syncthreads();
  if (threadIdx.x == 0) {
    float t1 = r1[0] + r1[1] + r1[2] + r1[3];
    float t2 = r2[0] + r2[1] + r2[2] + r2[3];
    gap[b * NC + c] = (t1 + t2) * (1.0f / HW);
  }
}

// ---------------------------------------------------------------------------
// Tiny MLP + training-mode BatchNorm (over batch of 4) + ReLU, one block.
// ---------------------------------------------------------------------------
__launch_bounds__(256)
__global__ void k_mlp(const float* __restrict__ gap,
                      const float* __restrict__ Wm1, const float* __restrict__ g1,
                      const float* __restrict__ b1,
                      const float* __restrict__ Wm2, const float* __restrict__ g2,
                      const float* __restrict__ b2, float* __restrict__ out) {
  __shared__ float gl[NB * NC];
  __shared__ float h[NB * MID];
  __shared__ float h1r[NB * MID];
  __shared__ float h2[NB * NOUT];
  const int tid = threadIdx.x;
  for (int i = tid; i < NB * NC; i += 256) gl[i] = gap[i];
  __syncthreads();

  if (tid < NB * MID) {
    int b = tid / MID, j = tid % MID;
    float acc = 0.f;
    #pragma unroll
    for (int c = 0; c < NC; ++c) acc += gl[b * NC + c] * Wm1[j * NC + c];
    h[b * MID + j] = acc;
  }
  __syncthreads();

  if (tid < MID) {
    float x0 = h[0 * MID + tid], x1 = h[1 * MID + tid];
    float x2 = h[2 * MID + tid], x3 = h[3 * MID + tid];
    float mu = 0.25f * (x0 + x1 + x2 + x3);
    float d0 = x0 - mu, d1 = x1 - mu, d2 = x2 - mu, d3 = x3 - mu;
    float v = 0.25f * (d0 * d0 + d1 * d1 + d2 * d2 + d3 * d3);
    float sc = g1[tid] * rsqrtf(v + BEPS);
    float bb = b1[tid];
    h1r[0 * MID + tid] = fmaxf(d0 * sc + bb, 0.f);
    h1r[1 * MID + tid] = fmaxf(d1 * sc + bb, 0.f);
    h1r[2 * MID + tid] = fmaxf(d2 * sc + bb, 0.f);
    h1r[3 * MID + tid] = fmaxf(d3 * sc + bb, 0.f);
  }
  __syncthreads();

  for (int idx = tid; idx < NB * NOUT; idx += 256) {
    int b = idx >> 8, o = idx & 255;
    float acc = 0.f;
    #pragma unroll
    for (int j = 0; j < MID; ++j) acc += h1r[b * MID + j] * Wm2[o * MID + j];
    h2[b * NOUT + o] = acc;
  }
  __syncthreads();

  if (tid < NOUT) {
    float x0 = h2[0 * NOUT + tid], x1 = h2[1 * NOUT + tid];
    float x2 = h2[2 * NOUT + tid], x3 = h2[3 * NOUT + tid];
    float mu = 0.25f * (x0 + x1 + x2 + x3);
    float d0 = x0 - mu, d1 = x1 - mu, d2 = x2 - mu, d3 = x3 - mu;
    float v = 0.25f * (d0 * d0 + d1 * d1 + d2 * d2 + d3 * d3);
    float sc = g2[tid] * rsqrtf(v + BEPS);
    float bb = b2[tid];
    out[0 * NOUT + tid] = fmaxf(d0 * sc + bb, 0.f);
    out[1 * NOUT + tid] = fmaxf(d1 * sc + bb, 0.f);
    out[2 * NOUT + tid] = fmaxf(d2 * sc + bb, 0.f);
    out[3 * NOUT + tid] = fmaxf(d3 * sc + bb, 0.f);
  }
}

// ---------------------------------------------------------------------------
extern "C" void kernel_launch(void* const* d_in, const int* in_sizes, int n_in,
                              void* d_out, int out_size, void* d_ws, size_t ws_size,
                              hipStream_t stream) {
  const float* rgb   = (const float*)d_in[0];
  const float* dep   = (const float*)d_in[1];
  const float* Wd    = (const float*)d_in[2];
  const float* Wr    = (const float*)d_in[3];
  const float* Wm1   = (const float*)d_in[4];
  const float* bn1_g = (const float*)d_in[5];
  const float* bn1_b = (const float*)d_in[6];
  const float* Wm2   = (const float*)d_in[7];
  const float* bn2_g = (const float*)d_in[8];
  const float* bn2_b = (const float*)d_in[9];
  float* out = (float*)d_out;

  char* w = (char*)d_ws;
  u16* prT2 = (u16*)w;            w += (size_t)NB * HW * 192 * 2;   // 6.3 MB
  u16* pdT2 = (u16*)w;            w += (size_t)NB * HW * 192 * 2;   // 6.3 MB
  float* psum  = (float*)w;       w += (size_t)NB * NC * HW * 4;    // 6.3 MB
  float* zpart = (float*)w;       w += (size_t)32 * NB * HW * 4;    // 2 MB
  float* nlz   = (float*)w;       w += (size_t)NB * HW * 4;
  float* spart = (float*)w;       w += (size_t)32 * NB * HW * 4;    // 2 MB
  float* sv    = (float*)w;       w += (size_t)NB * HW * 4;
  float* gap   = (float*)w;       w += (size_t)NB * NC * 4;

  k_prep<<<dim3(HW / 64, NB, 4), 256, 0, stream>>>(rgb, dep, Wr, Wd, psum, prT2, pdT2);
  k_energy<0><<<dim3(HW / 256, HW / 128, NB), 256, 0, stream>>>(prT2, pdT2, nullptr, zpart);
  k_zred<<<NB * HW / 256, 256, 0, stream>>>(zpart, nlz);
  k_energy<1><<<dim3(HW / 256, HW / 128, NB), 256, 0, stream>>>(pdT2, prT2, nlz, spart);
  k_sred<<<NB * HW / 256, 256, 0, stream>>>(spart, sv);
  k_gap<<<dim3(NC, NB), 256, 0, stream>>>(psum, rgb, dep, sv, gap);
  k_mlp<<<1, 256, 0, stream>>>(gap, Wm1, bn1_g, bn1_b, Wm2, bn2_g, bn2_b, out);
}

// Round 7
// 143.980 us; speedup vs baseline: 1.5385x; 1.0529x over previous
//
#include <hip/hip_runtime.h>

#define HW 4096
#define NC 96
#define NB 4
#define MID 24
#define NOUT 256
#define BEPS 1e-5f
#define SCALE_E 0.10206207261596575f  // 1/sqrt(96)

typedef unsigned short u16;
typedef short bf16x8 __attribute__((ext_vector_type(8)));
typedef unsigned short u16x8 __attribute__((ext_vector_type(8)));
typedef float f32x16 __attribute__((ext_vector_type(16)));

__device__ __forceinline__ u16 bfh(float x) {
  unsigned u = __float_as_uint(x);
  return (u16)((u + 0x7FFFu + ((u >> 16) & 1u)) >> 16);  // RNE bf16
}
__device__ __forceinline__ float bf2f(u16 h) {
  return __uint_as_float(((unsigned)h) << 16);
}

// ---------------------------------------------------------------------------
// Prep: pr = Wr*rgb, pd = Wd*dep; psum = pr+pd fp32 [b][c][n].
// Projections written in MFMA-FRAGMENT order:
//   chunk(tile = n>>5, ks = ch>>4, hl) of 512 u16 at
//     ((tile*12 + ks*2 + hl)<<9) + ((khalf*32 + (n&31))<<3) + (ch&7)
// so k_energy fragment loads are single coalesced 1KB global_load_dwordx4
// (lane = khalf*32 + row matches the 32x32x16 A/B operand mapping).
// ---------------------------------------------------------------------------
__launch_bounds__(256)
__global__ void k_prep(const float* __restrict__ rgb, const float* __restrict__ dep,
                       const float* __restrict__ Wr, const float* __restrict__ Wd,
                       float* __restrict__ psum, u16* __restrict__ prF, u16* __restrict__ pdF) {
  __shared__ u16 buf[2][64][48];   // [arr][n-local][hi24|lo24] for this quarter
  const int tid = threadIdx.x;
  const int slot = tid & 31;                                   // n-pair slot
  const int og = __builtin_amdgcn_readfirstlane(tid >> 6);     // wave-uniform o-group
  const int b = blockIdx.y, q = blockIdx.z;
  const int n0 = blockIdx.x * 64;
  const int obase = q * 24 + og * 6;

  float ar[6][2], ad[6][2];
  #pragma unroll
  for (int o = 0; o < 6; ++o) { ar[o][0] = ar[o][1] = ad[o][0] = ad[o][1] = 0.f; }

  const float* rb = rgb + (size_t)b * NC * HW + n0;
  const float* db = dep + (size_t)b * NC * HW + n0;
  #pragma unroll 4
  for (int c = 0; c < NC; ++c) {
    float2 xr = ((const float2*)(rb + (size_t)c * HW))[slot];
    float2 xd = ((const float2*)(db + (size_t)c * HW))[slot];
    #pragma unroll
    for (int o = 0; o < 6; ++o) {
      float wr = Wr[(obase + o) * NC + c];   // uniform -> s_load
      float wd = Wd[(obase + o) * NC + c];
      ar[o][0] = fmaf(wr, xr.x, ar[o][0]);
      ar[o][1] = fmaf(wr, xr.y, ar[o][1]);
      ad[o][0] = fmaf(wd, xd.x, ad[o][0]);
      ad[o][1] = fmaf(wd, xd.y, ad[o][1]);
    }
  }

  #pragma unroll
  for (int o = 0; o < 6; ++o) {
    float2 ps = make_float2(ar[o][0] + ad[o][0], ar[o][1] + ad[o][1]);
    *(float2*)&psum[((size_t)b * NC + obase + o) * HW + n0 + slot * 2] = ps;
    #pragma unroll
    for (int j = 0; j < 2; ++j) {
      int nl = slot * 2 + j;
      int ol = og * 6 + o;
      u16 h = bfh(ar[o][j]);
      buf[0][nl][ol] = h;
      buf[0][nl][24 + ol] = bfh(ar[o][j] - bf2f(h));
      u16 h2 = bfh(ad[o][j]);
      buf[1][nl][ol] = h2;
      buf[1][nl][24 + ol] = bfh(ad[o][j] - bf2f(h2));
    }
  }
  __syncthreads();

  // fragment-order writes: 2 arrays x 6 pieces x 64 rows of 16B.
  // piece 0..2 = hi chunks, 3..5 = lo; channels q*24+p*8..+8 -> c8 = q*3+p.
  for (int idx = tid; idx < 768; idx += 256) {
    int arr = idx / 384;
    int rem = idx % 384;
    int piece = rem >> 6;       // 0..5 (slow) -> coalesced rows within piece
    int nl = rem & 63;
    int hl = piece >= 3 ? 1 : 0;
    int p = piece - hl * 3;
    int c8 = q * 3 + p;         // global 8-ch chunk id 0..11
    int ks = c8 >> 1, khalf = c8 & 1;
    int tile = (n0 >> 5) + (nl >> 5);
    u16* dst = (arr ? pdF : prF) + (size_t)b * HW * 192
             + ((tile * 12 + ks * 2 + hl) << 9) + ((khalf * 32 + (nl & 31)) << 3);
    *(u16x8*)dst = *(const u16x8*)&buf[arr][nl][hl * 24 + p * 8];
  }
}

// ---------------------------------------------------------------------------
// MFMA energy pass, LDS-FREE: operands are L2-resident (12.6 MB total) and
// pre-arranged in fragment order -> every load is one coalesced 1KB
// global_load_dwordx4. No staging, no K-loop barriers.
// Block tile: 128 A-rows x 256 B-cols, 4 waves (2x2), wave tile 64x128.
// 3-term hi/lo bf16: e = Ah*Bh + Al*Bh + Ah*Bl  (~2^-17 rel).
// PASS 0: A=pr(n) B=pd(m): colsum over n of exp(e*s)          -> zpart
// PASS 1: A=pd(m) B=pr(n): colsum over m of exp(e*s - lnZ[m]) -> spart
// ---------------------------------------------------------------------------
template <int PASS>
__launch_bounds__(256, 2)
__global__ void k_energy(const u16* __restrict__ At, const u16* __restrict__ Bt,
                         const float* __restrict__ nlz, float* __restrict__ part) {
  __shared__ float red[2][256];
  const int tid = threadIdx.x;
  const int lane = tid & 63, wid = tid >> 6;
  const int wA = wid >> 1, wB = wid & 1;
  const int b = blockIdx.z;
  const int a0 = blockIdx.y * 128;
  const int c0 = blockIdx.x * 256;
  const u16* Ab = At + (size_t)b * HW * 192;
  const u16* Bb = Bt + (size_t)b * HW * 192;
  const int tA0 = blockIdx.y * 4 + wA * 2;   // 2 A-tiles of 32 rows
  const int tB0 = blockIdx.x * 8 + wB * 4;   // 4 B-tiles of 32 cols

  f32x16 acc[2][4];
  #pragma unroll
  for (int ta = 0; ta < 2; ++ta)
    #pragma unroll
    for (int tb = 0; tb < 4; ++tb)
      #pragma unroll
      for (int q = 0; q < 16; ++q) acc[ta][tb][q] = 0.f;

  #pragma unroll
  for (int ks = 0; ks < 6; ++ks) {
    bf16x8 ah[2], al[2];
    #pragma unroll
    for (int ta = 0; ta < 2; ++ta) {
      const u16* pa = Ab + (((tA0 + ta) * 12 + ks * 2) << 9) + (lane << 3);
      ah[ta] = *(const bf16x8*)pa;
      al[ta] = *(const bf16x8*)(pa + 512);
    }
    #pragma unroll
    for (int tb = 0; tb < 4; ++tb) {
      const u16* pb = Bb + (((tB0 + tb) * 12 + ks * 2) << 9) + (lane << 3);
      bf16x8 bh = *(const bf16x8*)pb;
      bf16x8 bl = *(const bf16x8*)(pb + 512);
      #pragma unroll
      for (int ta = 0; ta < 2; ++ta) {
        acc[ta][tb] = __builtin_amdgcn_mfma_f32_32x32x16_bf16(ah[ta], bh, acc[ta][tb], 0, 0, 0);
        acc[ta][tb] = __builtin_amdgcn_mfma_f32_32x32x16_bf16(al[ta], bh, acc[ta][tb], 0, 0, 0);
        acc[ta][tb] = __builtin_amdgcn_mfma_f32_32x32x16_bf16(ah[ta], bl, acc[ta][tb], 0, 0, 0);
      }
    }
  }

  // exp + column sums (over A-rows). C/D: col=lane&31, row=(q&3)+8*(q>>2)+4*(lane>>5)
  float csum[4] = {0.f, 0.f, 0.f, 0.f};
  float nlzv = 0.f;
  if (PASS) nlzv = nlz[(size_t)b * HW + a0 + wA * 64 + lane];
  #pragma unroll
  for (int ta = 0; ta < 2; ++ta) {
    #pragma unroll
    for (int q = 0; q < 16; ++q) {
      float bias = 0.f;
      if (PASS) {
        int src = ta * 32 + (q & 3) + 8 * (q >> 2) + 4 * (lane >> 5);
        bias = __shfl(nlzv, src, 64);
      }
      #pragma unroll
      for (int tb = 0; tb < 4; ++tb)
        csum[tb] += __expf(fmaf(acc[ta][tb][q], SCALE_E, bias));
    }
  }
  #pragma unroll
  for (int tb = 0; tb < 4; ++tb) csum[tb] += __shfl_xor(csum[tb], 32, 64);
  if (lane < 32) {
    #pragma unroll
    for (int tb = 0; tb < 4; ++tb) red[wA][wB * 128 + tb * 32 + lane] = csum[tb];
  }
  __syncthreads();
  part[((size_t)blockIdx.y * NB + b) * HW + c0 + tid] = red[0][tid] + red[1][tid];
}

// ---------------------------------------------------------------------------
__global__ void k_zred(const float* __restrict__ zpart, float* __restrict__ nlz) {
  int idx = blockIdx.x * 256 + threadIdx.x;  // over NB*HW
  float s = 0.f;
  #pragma unroll
  for (int t = 0; t < 32; ++t) s += zpart[(size_t)t * (NB * HW) + idx];
  nlz[idx] = -logf(s);
}

__global__ void k_sred(const float* __restrict__ spart, float* __restrict__ sv) {
  int idx = blockIdx.x * 256 + threadIdx.x;
  float a = 0.f;
  #pragma unroll
  for (int t = 0; t < 32; ++t) a += spart[(size_t)t * (NB * HW) + idx];
  sv[idx] = a;
}

// ---------------------------------------------------------------------------
// gap[b,c] = (1/HW)*[ sum_n psum[c,n]*s[n] + sum_n (rgb+dep)[c,n] ]
// ---------------------------------------------------------------------------
__launch_bounds__(256)
__global__ void k_gap(const float* __restrict__ psum, const float* __restrict__ rgb,
                      const float* __restrict__ dep, const float* __restrict__ sv,
                      float* __restrict__ gap) {
  const int c = blockIdx.x, b = blockIdx.y;
  const size_t off = ((size_t)b * NC + c) * HW;
  const float* pp = psum + off;
  const float* rp = rgb + off;
  const float* dp = dep + off;
  const float* sp = sv + (size_t)b * HW;
  float a1 = 0.f, a2 = 0.f;
  for (int n = threadIdx.x * 4; n < HW; n += 1024) {
    float4 p = *(const float4*)&pp[n];
    float4 s4 = *(const float4*)&sp[n];
    float4 r4 = *(const float4*)&rp[n];
    float4 d4 = *(const float4*)&dp[n];
    a1 += p.x * s4.x + p.y * s4.y + p.z * s4.z + p.w * s4.w;
    a2 += (r4.x + d4.x) + (r4.y + d4.y) + (r4.z + d4.z) + (r4.w + d4.w);
  }
  #pragma unroll
  for (int o = 32; o > 0; o >>= 1) {
    a1 += __shfl_down(a1, o, 64);
    a2 += __shfl_down(a2, o, 64);
  }
  __shared__ float r1[4], r2[4];
  const int wv = threadIdx.x >> 6;
  if ((threadIdx.x & 63) == 0) { r1[wv] = a1; r2[wv] = a2; }
  __syncthreads();
  if (threadIdx.x == 0) {
    float t1 = r1[0] + r1[1] + r1[2] + r1[3];
    float t2 = r2[0] + r2[1] + r2[2] + r2[3];
    gap[b * NC + c] = (t1 + t2) * (1.0f / HW);
  }
}

// ---------------------------------------------------------------------------
// Tiny MLP + training-mode BatchNorm (over batch of 4) + ReLU, one block.
// ---------------------------------------------------------------------------
__launch_bounds__(256)
__global__ void k_mlp(const float* __restrict__ gap,
                      const float* __restrict__ Wm1, const float* __restrict__ g1,
                      const float* __restrict__ b1,
                      const float* __restrict__ Wm2, const float* __restrict__ g2,
                      const float* __restrict__ b2, float* __restrict__ out) {
  __shared__ float gl[NB * NC];
  __shared__ float h[NB * MID];
  __shared__ float h1r[NB * MID];
  __shared__ float h2[NB * NOUT];
  const int tid = threadIdx.x;
  for (int i = tid; i < NB * NC; i += 256) gl[i] = gap[i];
  __syncthreads();

  if (tid < NB * MID) {
    int b = tid / MID, j = tid % MID;
    float acc = 0.f;
    #pragma unroll
    for (int c = 0; c < NC; ++c) acc += gl[b * NC + c] * Wm1[j * NC + c];
    h[b * MID + j] = acc;
  }
  __syncthreads();

  if (tid < MID) {
    float x0 = h[0 * MID + tid], x1 = h[1 * MID + tid];
    float x2 = h[2 * MID + tid], x3 = h[3 * MID + tid];
    float mu = 0.25f * (x0 + x1 + x2 + x3);
    float d0 = x0 - mu, d1 = x1 - mu, d2 = x2 - mu, d3 = x3 - mu;
    float v = 0.25f * (d0 * d0 + d1 * d1 + d2 * d2 + d3 * d3);
    float sc = g1[tid] * rsqrtf(v + BEPS);
    float bb = b1[tid];
    h1r[0 * MID + tid] = fmaxf(d0 * sc + bb, 0.f);
    h1r[1 * MID + tid] = fmaxf(d1 * sc + bb, 0.f);
    h1r[2 * MID + tid] = fmaxf(d2 * sc + bb, 0.f);
    h1r[3 * MID + tid] = fmaxf(d3 * sc + bb, 0.f);
  }
  __syncthreads();

  for (int idx = tid; idx < NB * NOUT; idx += 256) {
    int b = idx >> 8, o = idx & 255;
    float acc = 0.f;
    #pragma unroll
    for (int j = 0; j < MID; ++j) acc += h1r[b * MID + j] * Wm2[o * MID + j];
    h2[b * NOUT + o] = acc;
  }
  __syncthreads();

  if (tid < NOUT) {
    float x0 = h2[0 * NOUT + tid], x1 = h2[1 * NOUT + tid];
    float x2 = h2[2 * NOUT + tid], x3 = h2[3 * NOUT + tid];
    float mu = 0.25f * (x0 + x1 + x2 + x3);
    float d0 = x0 - mu, d1 = x1 - mu, d2 = x2 - mu, d3 = x3 - mu;
    float v = 0.25f * (d0 * d0 + d1 * d1 + d2 * d2 + d3 * d3);
    float sc = g2[tid] * rsqrtf(v + BEPS);
    float bb = b2[tid];
    out[0 * NOUT + tid] = fmaxf(d0 * sc + bb, 0.f);
    out[1 * NOUT + tid] = fmaxf(d1 * sc + bb, 0.f);
    out[2 * NOUT + tid] = fmaxf(d2 * sc + bb, 0.f);
    out[3 * NOUT + tid] = fmaxf(d3 * sc + bb, 0.f);
  }
}

// ---------------------------------------------------------------------------
extern "C" void kernel_launch(void* const* d_in, const int* in_sizes, int n_in,
                              void* d_out, int out_size, void* d_ws, size_t ws_size,
                              hipStream_t stream) {
  const float* rgb   = (const float*)d_in[0];
  const float* dep   = (const float*)d_in[1];
  const float* Wd    = (const float*)d_in[2];
  const float* Wr    = (const float*)d_in[3];
  const float* Wm1   = (const float*)d_in[4];
  const float* bn1_g = (const float*)d_in[5];
  const float* bn1_b = (const float*)d_in[6];
  const float* Wm2   = (const float*)d_in[7];
  const float* bn2_g = (const float*)d_in[8];
  const float* bn2_b = (const float*)d_in[9];
  float* out = (float*)d_out;

  char* w = (char*)d_ws;
  u16* prF = (u16*)w;             w += (size_t)NB * HW * 192 * 2;   // 6.3 MB frag-order
  u16* pdF = (u16*)w;             w += (size_t)NB * HW * 192 * 2;   // 6.3 MB frag-order
  float* psum  = (float*)w;       w += (size_t)NB * NC * HW * 4;    // 6.3 MB
  float* zpart = (float*)w;       w += (size_t)32 * NB * HW * 4;    // 2 MB
  float* nlz   = (float*)w;       w += (size_t)NB * HW * 4;
  float* spart = (float*)w;       w += (size_t)32 * NB * HW * 4;    // 2 MB
  float* sv    = (float*)w;       w += (size_t)NB * HW * 4;
  float* gap   = (float*)w;       w += (size_t)NB * NC * 4;

  k_prep<<<dim3(HW / 64, NB, 4), 256, 0, stream>>>(rgb, dep, Wr, Wd, psum, prF, pdF);
  k_energy<0><<<dim3(HW / 256, HW / 128, NB), 256, 0, stream>>>(prF, pdF, nullptr, zpart);
  k_zred<<<NB * HW / 256, 256, 0, stream>>>(zpart, nlz);
  k_energy<1><<<dim3(HW / 256, HW / 128, NB), 256, 0, stream>>>(pdF, prF, nlz, spart);
  k_sred<<<NB * HW / 256, 256, 0, stream>>>(spart, sv);
  k_gap<<<dim3(NC, NB), 256, 0, stream>>>(psum, rgb, dep, sv, gap);
  k_mlp<<<1, 256, 0, stream>>>(gap, Wm1, bn1_g, bn1_b, Wm2, bn2_g, bn2_b, out);
}

// Round 8
// 125.308 us; speedup vs baseline: 1.7678x; 1.1490x over previous
//
#include <hip/hip_runtime.h>

#define HW 4096
#define NC 96
#define NB 4
#define MID 24
#define NOUT 256
#define BEPS 1e-5f
#define SCALE_E 0.10206207261596575f  // 1/sqrt(96)

typedef unsigned short u16;
typedef short bf16x8 __attribute__((ext_vector_type(8)));
typedef unsigned short u16x8 __attribute__((ext_vector_type(8)));
typedef float f32x16 __attribute__((ext_vector_type(16)));

__device__ __forceinline__ u16 bfh(float x) {
  unsigned u = __float_as_uint(x);
  return (u16)((u + 0x7FFFu + ((u >> 16) & 1u)) >> 16);  // RNE bf16
}
__device__ __forceinline__ float bf2f(u16 h) {
  return __uint_as_float(((unsigned)h) << 16);
}

// ---------------------------------------------------------------------------
// Prep: pr = Wr*rgb, pd = Wd*dep; psum = pr+pd fp32 [b][c][n].
// Projections written in MFMA-FRAGMENT order:
//   chunk(tile = n>>5, ks = ch>>4, hl) of 512 u16 at
//     ((tile*12 + ks*2 + hl)<<9) + ((khalf*32 + (n&31))<<3) + (ch&7)
// so k_energy fragment loads are single coalesced 1KB global_load_dwordx4.
// ---------------------------------------------------------------------------
__launch_bounds__(256)
__global__ void k_prep(const float* __restrict__ rgb, const float* __restrict__ dep,
                       const float* __restrict__ Wr, const float* __restrict__ Wd,
                       float* __restrict__ psum, u16* __restrict__ prF, u16* __restrict__ pdF) {
  __shared__ u16 buf[2][64][48];   // [arr][n-local][hi24|lo24] for this quarter
  const int tid = threadIdx.x;
  const int slot = tid & 31;                                   // n-pair slot
  const int og = __builtin_amdgcn_readfirstlane(tid >> 6);     // wave-uniform o-group
  const int b = blockIdx.y, q = blockIdx.z;
  const int n0 = blockIdx.x * 64;
  const int obase = q * 24 + og * 6;

  float ar[6][2], ad[6][2];
  #pragma unroll
  for (int o = 0; o < 6; ++o) { ar[o][0] = ar[o][1] = ad[o][0] = ad[o][1] = 0.f; }

  const float* rb = rgb + (size_t)b * NC * HW + n0;
  const float* db = dep + (size_t)b * NC * HW + n0;
  #pragma unroll 4
  for (int c = 0; c < NC; ++c) {
    float2 xr = ((const float2*)(rb + (size_t)c * HW))[slot];
    float2 xd = ((const float2*)(db + (size_t)c * HW))[slot];
    #pragma unroll
    for (int o = 0; o < 6; ++o) {
      float wr = Wr[(obase + o) * NC + c];   // uniform -> s_load
      float wd = Wd[(obase + o) * NC + c];
      ar[o][0] = fmaf(wr, xr.x, ar[o][0]);
      ar[o][1] = fmaf(wr, xr.y, ar[o][1]);
      ad[o][0] = fmaf(wd, xd.x, ad[o][0]);
      ad[o][1] = fmaf(wd, xd.y, ad[o][1]);
    }
  }

  #pragma unroll
  for (int o = 0; o < 6; ++o) {
    float2 ps = make_float2(ar[o][0] + ad[o][0], ar[o][1] + ad[o][1]);
    *(float2*)&psum[((size_t)b * NC + obase + o) * HW + n0 + slot * 2] = ps;
    #pragma unroll
    for (int j = 0; j < 2; ++j) {
      int nl = slot * 2 + j;
      int ol = og * 6 + o;
      u16 h = bfh(ar[o][j]);
      buf[0][nl][ol] = h;
      buf[0][nl][24 + ol] = bfh(ar[o][j] - bf2f(h));
      u16 h2 = bfh(ad[o][j]);
      buf[1][nl][ol] = h2;
      buf[1][nl][24 + ol] = bfh(ad[o][j] - bf2f(h2));
    }
  }
  __syncthreads();

  // fragment-order writes: 2 arrays x 6 pieces x 64 rows of 16B.
  for (int idx = tid; idx < 768; idx += 256) {
    int arr = idx / 384;
    int rem = idx % 384;
    int piece = rem >> 6;       // 0..5
    int nl = rem & 63;
    int hl = piece >= 3 ? 1 : 0;
    int p = piece - hl * 3;
    int c8 = q * 3 + p;         // global 8-ch chunk id 0..11
    int ks = c8 >> 1, khalf = c8 & 1;
    int tile = (n0 >> 5) + (nl >> 5);
    u16* dst = (arr ? pdF : prF) + (size_t)b * HW * 192
             + ((tile * 12 + ks * 2 + hl) << 9) + ((khalf * 32 + (nl & 31)) << 3);
    *(u16x8*)dst = *(const u16x8*)&buf[arr][nl][hl * 24 + p * 8];
  }
}

// ---------------------------------------------------------------------------
// MFMA energy pass, LDS-free, latency-tuned:
//  - wave tile 64x64 (acc[2][2] = 64 AGPR) -> ~3 waves/SIMD occupancy
//  - block tile 128x128, 4 waves (2x2); grid (32,32,NB)
//  - XCD-chunked bijective swizzle: by=(flat&7)*4+((flat>>3)&3), bx=flat>>5
//    -> each XCD keeps its 4 A-row-tiles L2-resident and walks B with 4x
//       back-to-back reuse (B from L3 once per XCD).
// 3-term hi/lo bf16: e = Ah*Bh + Al*Bh + Ah*Bl  (~2^-17 rel).
// PASS 0: A=pr(n) B=pd(m): colsum over n of exp(e*s)          -> zpart
// PASS 1: A=pd(m) B=pr(n): colsum over m of exp(e*s - lnZ[m]) -> spart
// ---------------------------------------------------------------------------
template <int PASS>
__launch_bounds__(256)
__global__ void k_energy(const u16* __restrict__ At, const u16* __restrict__ Bt,
                         const float* __restrict__ nlz, float* __restrict__ part) {
  __shared__ float red[2][128];
  const int tid = threadIdx.x;
  const int lane = tid & 63, wid = tid >> 6;
  const int wA = wid >> 1, wB = wid & 1;
  const int b = blockIdx.z;
  const int flat = blockIdx.y * 32 + blockIdx.x;   // 0..1023
  const int by = (flat & 7) * 4 + ((flat >> 3) & 3);
  const int bx = flat >> 5;
  const int a0 = by * 128;
  const int c0 = bx * 128;
  const u16* Ab = At + (size_t)b * HW * 192;
  const u16* Bb = Bt + (size_t)b * HW * 192;
  const int tA0 = by * 4 + wA * 2;   // 2 A-tiles of 32 rows
  const int tB0 = bx * 4 + wB * 2;   // 2 B-tiles of 32 cols

  f32x16 acc[2][2];
  #pragma unroll
  for (int ta = 0; ta < 2; ++ta)
    #pragma unroll
    for (int tb = 0; tb < 2; ++tb)
      #pragma unroll
      for (int q = 0; q < 16; ++q) acc[ta][tb][q] = 0.f;

  #pragma unroll
  for (int ks = 0; ks < 6; ++ks) {
    bf16x8 ah[2], al[2];
    #pragma unroll
    for (int ta = 0; ta < 2; ++ta) {
      const u16* pa = Ab + (((tA0 + ta) * 12 + ks * 2) << 9) + (lane << 3);
      ah[ta] = *(const bf16x8*)pa;
      al[ta] = *(const bf16x8*)(pa + 512);
    }
    #pragma unroll
    for (int tb = 0; tb < 2; ++tb) {
      const u16* pb = Bb + (((tB0 + tb) * 12 + ks * 2) << 9) + (lane << 3);
      bf16x8 bh = *(const bf16x8*)pb;
      bf16x8 bl = *(const bf16x8*)(pb + 512);
      #pragma unroll
      for (int ta = 0; ta < 2; ++ta) {
        acc[ta][tb] = __builtin_amdgcn_mfma_f32_32x32x16_bf16(ah[ta], bh, acc[ta][tb], 0, 0, 0);
        acc[ta][tb] = __builtin_amdgcn_mfma_f32_32x32x16_bf16(al[ta], bh, acc[ta][tb], 0, 0, 0);
        acc[ta][tb] = __builtin_amdgcn_mfma_f32_32x32x16_bf16(ah[ta], bl, acc[ta][tb], 0, 0, 0);
      }
    }
  }

  // exp + column sums (over A-rows). C/D: col=lane&31, row=(q&3)+8*(q>>2)+4*(lane>>5)
  float csum[2] = {0.f, 0.f};
  float nlzv = 0.f;
  if (PASS) nlzv = nlz[(size_t)b * HW + a0 + wA * 64 + lane];
  #pragma unroll
  for (int ta = 0; ta < 2; ++ta) {
    #pragma unroll
    for (int q = 0; q < 16; ++q) {
      float bias = 0.f;
      if (PASS) {
        int src = ta * 32 + (q & 3) + 8 * (q >> 2) + 4 * (lane >> 5);
        bias = __shfl(nlzv, src, 64);
      }
      #pragma unroll
      for (int tb = 0; tb < 2; ++tb)
        csum[tb] += __expf(fmaf(acc[ta][tb][q], SCALE_E, bias));
    }
  }
  #pragma unroll
  for (int tb = 0; tb < 2; ++tb) csum[tb] += __shfl_xor(csum[tb], 32, 64);
  if (lane < 32) {
    #pragma unroll
    for (int tb = 0; tb < 2; ++tb) red[wA][wB * 64 + tb * 32 + lane] = csum[tb];
  }
  __syncthreads();
  if (tid < 128)
    part[((size_t)by * NB + b) * HW + c0 + tid] = red[0][tid] + red[1][tid];
}

// ---------------------------------------------------------------------------
__global__ void k_zred(const float* __restrict__ zpart, float* __restrict__ nlz) {
  int idx = blockIdx.x * 256 + threadIdx.x;  // over NB*HW
  float s = 0.f;
  #pragma unroll
  for (int t = 0; t < 32; ++t) s += zpart[(size_t)t * (NB * HW) + idx];
  nlz[idx] = -logf(s);
}

__global__ void k_sred(const float* __restrict__ spart, float* __restrict__ sv) {
  int idx = blockIdx.x * 256 + threadIdx.x;
  float a = 0.f;
  #pragma unroll
  for (int t = 0; t < 32; ++t) a += spart[(size_t)t * (NB * HW) + idx];
  sv[idx] = a;
}

// ---------------------------------------------------------------------------
// gap[b,c] = (1/HW)*[ sum_n psum[c,n]*s[n] + sum_n (rgb+dep)[c,n] ]
// ---------------------------------------------------------------------------
__launch_bounds__(256)
__global__ void k_gap(const float* __restrict__ psum, const float* __restrict__ rgb,
                      const float* __restrict__ dep, const float* __restrict__ sv,
                      float* __restrict__ gap) {
  const int c = blockIdx.x, b = blockIdx.y;
  const size_t off = ((size_t)b * NC + c) * HW;
  const float* pp = psum + off;
  const float* rp = rgb + off;
  const float* dp = dep + off;
  const float* sp = sv + (size_t)b * HW;
  float a1 = 0.f, a2 = 0.f;
  for (int n = threadIdx.x * 4; n < HW; n += 1024) {
    float4 p = *(const float4*)&pp[n];
    float4 s4 = *(const float4*)&sp[n];
    float4 r4 = *(const float4*)&rp[n];
    float4 d4 = *(const float4*)&dp[n];
    a1 += p.x * s4.x + p.y * s4.y + p.z * s4.z + p.w * s4.w;
    a2 += (r4.x + d4.x) + (r4.y + d4.y) + (r4.z + d4.z) + (r4.w + d4.w);
  }
  #pragma unroll
  for (int o = 32; o > 0; o >>= 1) {
    a1 += __shfl_down(a1, o, 64);
    a2 += __shfl_down(a2, o, 64);
  }
  __shared__ float r1[4], r2[4];
  const int wv = threadIdx.x >> 6;
  if ((threadIdx.x & 63) == 0) { r1[wv] = a1; r2[wv] = a2; }
  __syncthreads();
  if (threadIdx.x == 0) {
    float t1 = r1[0] + r1[1] + r1[2] + r1[3];
    float t2 = r2[0] + r2[1] + r2[2] + r2[3];
    gap[b * NC + c] = (t1 + t2) * (1.0f / HW);
  }
}

// ---------------------------------------------------------------------------
// Tiny MLP + training-mode BatchNorm (over batch of 4) + ReLU, one block.
// ---------------------------------------------------------------------------
__launch_bounds__(256)
__global__ void k_mlp(const float* __restrict__ gap,
                      const float* __restrict__ Wm1, const float* __restrict__ g1,
                      const float* __restrict__ b1,
                      const float* __restrict__ Wm2, const float* __restrict__ g2,
                      const float* __restrict__ b2, float* __restrict__ out) {
  __shared__ float gl[NB * NC];
  __shared__ float h[NB * MID];
  __shared__ float h1r[NB * MID];
  __shared__ float h2[NB * NOUT];
  const int tid = threadIdx.x;
  for (int i = tid; i < NB * NC; i += 256) gl[i] = gap[i];
  __syncthreads();

  if (tid < NB * MID) {
    int b = tid / MID, j = tid % MID;
    float acc = 0.f;
    #pragma unroll
    for (int c = 0; c < NC; ++c) acc += gl[b * NC + c] * Wm1[j * NC + c];
    h[b * MID + j] = acc;
  }
  __syncthreads();

  if (tid < MID) {
    float x0 = h[0 * MID + tid], x1 = h[1 * MID + tid];
    float x2 = h[2 * MID + tid], x3 = h[3 * MID + tid];
    float mu = 0.25f * (x0 + x1 + x2 + x3);
    float d0 = x0 - mu, d1 = x1 - mu, d2 = x2 - mu, d3 = x3 - mu;
    float v = 0.25f * (d0 * d0 + d1 * d1 + d2 * d2 + d3 * d3);
    float sc = g1[tid] * rsqrtf(v + BEPS);
    float bb = b1[tid];
    h1r[0 * MID + tid] = fmaxf(d0 * sc + bb, 0.f);
    h1r[1 * MID + tid] = fmaxf(d1 * sc + bb, 0.f);
    h1r[2 * MID + tid] = fmaxf(d2 * sc + bb, 0.f);
    h1r[3 * MID + tid] = fmaxf(d3 * sc + bb, 0.f);
  }
  __syncthreads();

  for (int idx = tid; idx < NB * NOUT; idx += 256) {
    int b = idx >> 8, o = idx & 255;
    float acc = 0.f;
    #pragma unroll
    for (int j = 0; j < MID; ++j) acc += h1r[b * MID + j] * Wm2[o * MID + j];
    h2[b * NOUT + o] = acc;
  }
  __syncthreads();

  if (tid < NOUT) {
    float x0 = h2[0 * NOUT + tid], x1 = h2[1 * NOUT + tid];
    float x2 = h2[2 * NOUT + tid], x3 = h2[3 * NOUT + tid];
    float mu = 0.25f * (x0 + x1 + x2 + x3);
    float d0 = x0 - mu, d1 = x1 - mu, d2 = x2 - mu, d3 = x3 - mu;
    float v = 0.25f * (d0 * d0 + d1 * d1 + d2 * d2 + d3 * d3);
    float sc = g2[tid] * rsqrtf(v + BEPS);
    float bb = b2[tid];
    out[0 * NOUT + tid] = fmaxf(d0 * sc + bb, 0.f);
    out[1 * NOUT + tid] = fmaxf(d1 * sc + bb, 0.f);
    out[2 * NOUT + tid] = fmaxf(d2 * sc + bb, 0.f);
    out[3 * NOUT + tid] = fmaxf(d3 * sc + bb, 0.f);
  }
}

// ---------------------------------------------------------------------------
extern "C" void kernel_launch(void* const* d_in, const int* in_sizes, int n_in,
                              void* d_out, int out_size, void* d_ws, size_t ws_size,
                              hipStream_t stream) {
  const float* rgb   = (const float*)d_in[0];
  const float* dep   = (const float*)d_in[1];
  const float* Wd    = (const float*)d_in[2];
  const float* Wr    = (const float*)d_in[3];
  const float* Wm1   = (const float*)d_in[4];
  const float* bn1_g = (const float*)d_in[5];
  const float* bn1_b = (const float*)d_in[6];
  const float* Wm2   = (const float*)d_in[7];
  const float* bn2_g = (const float*)d_in[8];
  const float* bn2_b = (const float*)d_in[9];
  float* out = (float*)d_out;

  char* w = (char*)d_ws;
  u16* prF = (u16*)w;             w += (size_t)NB * HW * 192 * 2;   // 6.3 MB frag-order
  u16* pdF = (u16*)w;             w += (size_t)NB * HW * 192 * 2;   // 6.3 MB frag-order
  float* psum  = (float*)w;       w += (size_t)NB * NC * HW * 4;    // 6.3 MB
  float* zpart = (float*)w;       w += (size_t)32 * NB * HW * 4;    // 2 MB
  float* nlz   = (float*)w;       w += (size_t)NB * HW * 4;
  float* spart = (float*)w;       w += (size_t)32 * NB * HW * 4;    // 2 MB
  float* sv    = (float*)w;       w += (size_t)NB * HW * 4;
  float* gap   = (float*)w;       w += (size_t)NB * NC * 4;

  k_prep<<<dim3(HW / 64, NB, 4), 256, 0, stream>>>(rgb, dep, Wr, Wd, psum, prF, pdF);
  k_energy<0><<<dim3(32, 32, NB), 256, 0, stream>>>(prF, pdF, nullptr, zpart);
  k_zred<<<NB * HW / 256, 256, 0, stream>>>(zpart, nlz);
  k_energy<1><<<dim3(32, 32, NB), 256, 0, stream>>>(pdF, prF, nlz, spart);
  k_sred<<<NB * HW / 256, 256, 0, stream>>>(spart, sv);
  k_gap<<<dim3(NC, NB), 256, 0, stream>>>(psum, rgb, dep, sv, gap);
  k_mlp<<<1, 256, 0, stream>>>(gap, Wm1, bn1_g, bn1_b, Wm2, bn2_g, bn2_b, out);
}

// Round 9
// 99.810 us; speedup vs baseline: 2.2194x; 1.2555x over previous
//
#include <hip/hip_runtime.h>

#define HW 4096
#define NC 96
#define NB 4
#define MID 24
#define NOUT 256
#define BEPS 1e-5f
#define SCALE_E 0.10206207261596575f  // 1/sqrt(96)

typedef unsigned short u16;
typedef short bf16x8 __attribute__((ext_vector_type(8)));
typedef unsigned short u16x8 __attribute__((ext_vector_type(8)));
typedef float f32x16 __attribute__((ext_vector_type(16)));

__device__ __forceinline__ u16 bfh(float x) {
  unsigned u = __float_as_uint(x);
  return (u16)((u + 0x7FFFu + ((u >> 16) & 1u)) >> 16);  // RNE bf16
}
__device__ __forceinline__ float bf2f(u16 h) {
  return __uint_as_float(((unsigned)h) << 16);
}

// ---------------------------------------------------------------------------
// Prep: pr = Wr*rgb, pd = Wd*dep; psum = pr+pd fp32 [b][c][n].
// Fragment-order hi/lo bf16 operand arrays for k_energy.
// FIXED r8 bug: slot = tid&63 (was &31: half the block duplicated work).
// Block covers 128 n x 24 ch; grid (HW/128, NB, 4 o-quarters).
// ---------------------------------------------------------------------------
__launch_bounds__(256)
__global__ void k_prep(const float* __restrict__ rgb, const float* __restrict__ dep,
                       const float* __restrict__ Wr, const float* __restrict__ Wd,
                       float* __restrict__ psum, u16* __restrict__ prF, u16* __restrict__ pdF) {
  __shared__ u16 buf[2][128][48];   // [arr][n-local][hi24|lo24], 24.5 KB
  const int tid = threadIdx.x;
  const int slot = tid & 63;                                   // n-pair slot (64 per wave)
  const int og = __builtin_amdgcn_readfirstlane(tid >> 6);     // wave-uniform o-group
  const int b = blockIdx.y, q = blockIdx.z;
  const int n0 = blockIdx.x * 128;
  const int obase = q * 24 + og * 6;

  float ar[6][2], ad[6][2];
  #pragma unroll
  for (int o = 0; o < 6; ++o) { ar[o][0] = ar[o][1] = ad[o][0] = ad[o][1] = 0.f; }

  const float* rb = rgb + (size_t)b * NC * HW + n0;
  const float* db = dep + (size_t)b * NC * HW + n0;
  #pragma unroll 4
  for (int c = 0; c < NC; ++c) {
    float2 xr = ((const float2*)(rb + (size_t)c * HW))[slot];
    float2 xd = ((const float2*)(db + (size_t)c * HW))[slot];
    #pragma unroll
    for (int o = 0; o < 6; ++o) {
      float wr = Wr[(obase + o) * NC + c];   // uniform -> s_load
      float wd = Wd[(obase + o) * NC + c];
      ar[o][0] = fmaf(wr, xr.x, ar[o][0]);
      ar[o][1] = fmaf(wr, xr.y, ar[o][1]);
      ad[o][0] = fmaf(wd, xd.x, ad[o][0]);
      ad[o][1] = fmaf(wd, xd.y, ad[o][1]);
    }
  }

  #pragma unroll
  for (int o = 0; o < 6; ++o) {
    float2 ps = make_float2(ar[o][0] + ad[o][0], ar[o][1] + ad[o][1]);
    *(float2*)&psum[((size_t)b * NC + obase + o) * HW + n0 + slot * 2] = ps;
    #pragma unroll
    for (int j = 0; j < 2; ++j) {
      int nl = slot * 2 + j;
      int ol = og * 6 + o;
      u16 h = bfh(ar[o][j]);
      buf[0][nl][ol] = h;
      buf[0][nl][24 + ol] = bfh(ar[o][j] - bf2f(h));
      u16 h2 = bfh(ad[o][j]);
      buf[1][nl][ol] = h2;
      buf[1][nl][24 + ol] = bfh(ad[o][j] - bf2f(h2));
    }
  }
  __syncthreads();

  // fragment-order writes: 2 arrays x 6 pieces x 128 rows of 16B.
  for (int idx = tid; idx < 1536; idx += 256) {
    int arr = idx / 768;
    int rem = idx % 768;
    int piece = rem >> 7;       // 0..5
    int nl = rem & 127;
    int hl = piece >= 3 ? 1 : 0;
    int p = piece - hl * 3;
    int c8 = q * 3 + p;         // global 8-ch chunk id 0..11
    int ks = c8 >> 1, khalf = c8 & 1;
    int tile = (n0 >> 5) + (nl >> 5);
    u16* dst = (arr ? pdF : prF) + (size_t)b * HW * 192
             + ((tile * 12 + ks * 2 + hl) << 9) + ((khalf * 32 + (nl & 31)) << 3);
    *(u16x8*)dst = *(const u16x8*)&buf[arr][nl][hl * 24 + p * 8];
  }
}

// ---------------------------------------------------------------------------
// MFMA energy pass, LDS-free, register-pinned A:
//  - ALL 24 A-fragment loads (2 tiles x 6 ks x hi/lo = 96 VGPR) issued
//    upfront -> 24-deep load queue swallows L2 latency once.
//  - 2-term hi/lo split: e ~= (Ah+Al)*Bh  (drops Ah*Bl, ~5e-4 std on scaled
//    e vs 3.45e-2 threshold). 8 MFMA + 2 B-loads per ks.
//  - wave tile 64x64 (acc[2][2] = 64 AGPR), block 128x128, grid (32,32,NB)
//  - XCD-chunked swizzle: by=(flat&7)*4+((flat>>3)&3), bx=flat>>5.
// PASS 0: A=pr(n) B=pd(m): colsum over n of exp(e*s)          -> zpart
// PASS 1: A=pd(m) B=pr(n): colsum over m of exp(e*s - lnZ[m]) -> spart
// ---------------------------------------------------------------------------
template <int PASS>
__launch_bounds__(256, 2)
__global__ void k_energy(const u16* __restrict__ At, const u16* __restrict__ Bt,
                         const float* __restrict__ nlz, float* __restrict__ part) {
  __shared__ float red[2][128];
  const int tid = threadIdx.x;
  const int lane = tid & 63, wid = tid >> 6;
  const int wA = wid >> 1, wB = wid & 1;
  const int b = blockIdx.z;
  const int flat = blockIdx.y * 32 + blockIdx.x;   // 0..1023
  const int by = (flat & 7) * 4 + ((flat >> 3) & 3);
  const int bx = flat >> 5;
  const int a0 = by * 128;
  const int c0 = bx * 128;
  const u16* Ab = At + (size_t)b * HW * 192;
  const u16* Bb = Bt + (size_t)b * HW * 192;
  const int tA0 = by * 4 + wA * 2;   // 2 A-tiles of 32 rows
  const int tB0 = bx * 4 + wB * 2;   // 2 B-tiles of 32 cols

  // pin all A fragments in registers (96 VGPR), deep in-flight queue
  bf16x8 Ah[2][6], Al[2][6];
  #pragma unroll
  for (int ta = 0; ta < 2; ++ta)
    #pragma unroll
    for (int ks = 0; ks < 6; ++ks) {
      const u16* pa = Ab + (((tA0 + ta) * 12 + ks * 2) << 9) + (lane << 3);
      Ah[ta][ks] = *(const bf16x8*)pa;
      Al[ta][ks] = *(const bf16x8*)(pa + 512);
    }

  f32x16 acc[2][2];
  #pragma unroll
  for (int ta = 0; ta < 2; ++ta)
    #pragma unroll
    for (int tb = 0; tb < 2; ++tb)
      #pragma unroll
      for (int q = 0; q < 16; ++q) acc[ta][tb][q] = 0.f;

  #pragma unroll
  for (int ks = 0; ks < 6; ++ks) {
    #pragma unroll
    for (int tb = 0; tb < 2; ++tb) {
      const u16* pb = Bb + (((tB0 + tb) * 12 + ks * 2) << 9) + (lane << 3);
      bf16x8 bh = *(const bf16x8*)pb;   // B hi only (2-term)
      #pragma unroll
      for (int ta = 0; ta < 2; ++ta) {
        acc[ta][tb] = __builtin_amdgcn_mfma_f32_32x32x16_bf16(Ah[ta][ks], bh, acc[ta][tb], 0, 0, 0);
        acc[ta][tb] = __builtin_amdgcn_mfma_f32_32x32x16_bf16(Al[ta][ks], bh, acc[ta][tb], 0, 0, 0);
      }
    }
  }

  // exp + column sums (over A-rows). C/D: col=lane&31, row=(q&3)+8*(q>>2)+4*(lane>>5)
  float csum[2] = {0.f, 0.f};
  float nlzv = 0.f;
  if (PASS) nlzv = nlz[(size_t)b * HW + a0 + wA * 64 + lane];
  #pragma unroll
  for (int ta = 0; ta < 2; ++ta) {
    #pragma unroll
    for (int q = 0; q < 16; ++q) {
      float bias = 0.f;
      if (PASS) {
        int src = ta * 32 + (q & 3) + 8 * (q >> 2) + 4 * (lane >> 5);
        bias = __shfl(nlzv, src, 64);
      }
      #pragma unroll
      for (int tb = 0; tb < 2; ++tb)
        csum[tb] += __expf(fmaf(acc[ta][tb][q], SCALE_E, bias));
    }
  }
  #pragma unroll
  for (int tb = 0; tb < 2; ++tb) csum[tb] += __shfl_xor(csum[tb], 32, 64);
  if (lane < 32) {
    #pragma unroll
    for (int tb = 0; tb < 2; ++tb) red[wA][wB * 64 + tb * 32 + lane] = csum[tb];
  }
  __syncthreads();
  if (tid < 128)
    part[((size_t)by * NB + b) * HW + c0 + tid] = red[0][tid] + red[1][tid];
}

// ---------------------------------------------------------------------------
__global__ void k_zred(const float* __restrict__ zpart, float* __restrict__ nlz) {
  int idx = blockIdx.x * 256 + threadIdx.x;  // over NB*HW
  float s = 0.f;
  #pragma unroll
  for (int t = 0; t < 32; ++t) s += zpart[(size_t)t * (NB * HW) + idx];
  nlz[idx] = -logf(s);
}

__global__ void k_sred(const float* __restrict__ spart, float* __restrict__ sv) {
  int idx = blockIdx.x * 256 + threadIdx.x;
  float a = 0.f;
  #pragma unroll
  for (int t = 0; t < 32; ++t) a += spart[(size_t)t * (NB * HW) + idx];
  sv[idx] = a;
}

// ---------------------------------------------------------------------------
// gap[b,c] = (1/HW)*[ sum_n psum[c,n]*s[n] + sum_n (rgb+dep)[c,n] ]
// ---------------------------------------------------------------------------
__launch_bounds__(256)
__global__ void k_gap(const float* __restrict__ psum, const float* __restrict__ rgb,
                      const float* __restrict__ dep, const float* __restrict__ sv,
                      float* __restrict__ gap) {
  const int c = blockIdx.x, b = blockIdx.y;
  const size_t off = ((size_t)b * NC + c) * HW;
  const float* pp = psum + off;
  const float* rp = rgb + off;
  const float* dp = dep + off;
  const float* sp = sv + (size_t)b * HW;
  float a1 = 0.f, a2 = 0.f;
  for (int n = threadIdx.x * 4; n < HW; n += 1024) {
    float4 p = *(const float4*)&pp[n];
    float4 s4 = *(const float4*)&sp[n];
    float4 r4 = *(const float4*)&rp[n];
    float4 d4 = *(const float4*)&dp[n];
    a1 += p.x * s4.x + p.y * s4.y + p.z * s4.z + p.w * s4.w;
    a2 += (r4.x + d4.x) + (r4.y + d4.y) + (r4.z + d4.z) + (r4.w + d4.w);
  }
  #pragma unroll
  for (int o = 32; o > 0; o >>= 1) {
    a1 += __shfl_down(a1, o, 64);
    a2 += __shfl_down(a2, o, 64);
  }
  __shared__ float r1[4], r2[4];
  const int wv = threadIdx.x >> 6;
  if ((threadIdx.x & 63) == 0) { r1[wv] = a1; r2[wv] = a2; }
  __syncthreads();
  if (threadIdx.x == 0) {
    float t1 = r1[0] + r1[1] + r1[2] + r1[3];
    float t2 = r2[0] + r2[1] + r2[2] + r2[3];
    gap[b * NC + c] = (t1 + t2) * (1.0f / HW);
  }
}

// ---------------------------------------------------------------------------
// Tiny MLP + training-mode BatchNorm (over batch of 4) + ReLU, one block.
// ---------------------------------------------------------------------------
__launch_bounds__(256)
__global__ void k_mlp(const float* __restrict__ gap,
                      const float* __restrict__ Wm1, const float* __restrict__ g1,
                      const float* __restrict__ b1,
                      const float* __restrict__ Wm2, const float* __restrict__ g2,
                      const float* __restrict__ b2, float* __restrict__ out) {
  __shared__ float gl[NB * NC];
  __shared__ float h[NB * MID];
  __shared__ float h1r[NB * MID];
  __shared__ float h2[NB * NOUT];
  const int tid = threadIdx.x;
  for (int i = tid; i < NB * NC; i += 256) gl[i] = gap[i];
  __syncthreads();

  if (tid < NB * MID) {
    int b = tid / MID, j = tid % MID;
    float acc = 0.f;
    #pragma unroll
    for (int c = 0; c < NC; ++c) acc += gl[b * NC + c] * Wm1[j * NC + c];
    h[b * MID + j] = acc;
  }
  __syncthreads();

  if (tid < MID) {
    float x0 = h[0 * MID + tid], x1 = h[1 * MID + tid];
    float x2 = h[2 * MID + tid], x3 = h[3 * MID + tid];
    float mu = 0.25f * (x0 + x1 + x2 + x3);
    float d0 = x0 - mu, d1 = x1 - mu, d2 = x2 - mu, d3 = x3 - mu;
    float v = 0.25f * (d0 * d0 + d1 * d1 + d2 * d2 + d3 * d3);
    float sc = g1[tid] * rsqrtf(v + BEPS);
    float bb = b1[tid];
    h1r[0 * MID + tid] = fmaxf(d0 * sc + bb, 0.f);
    h1r[1 * MID + tid] = fmaxf(d1 * sc + bb, 0.f);
    h1r[2 * MID + tid] = fmaxf(d2 * sc + bb, 0.f);
    h1r[3 * MID + tid] = fmaxf(d3 * sc + bb, 0.f);
  }
  __syncthreads();

  for (int idx = tid; idx < NB * NOUT; idx += 256) {
    int b = idx >> 8, o = idx & 255;
    float acc = 0.f;
    #pragma unroll
    for (int j = 0; j < MID; ++j) acc += h1r[b * MID + j] * Wm2[o * MID + j];
    h2[b * NOUT + o] = acc;
  }
  __syncthreads();

  if (tid < NOUT) {
    float x0 = h2[0 * NOUT + tid], x1 = h2[1 * NOUT + tid];
    float x2 = h2[2 * NOUT + tid], x3 = h2[3 * NOUT + tid];
    float mu = 0.25f * (x0 + x1 + x2 + x3);
    float d0 = x0 - mu, d1 = x1 - mu, d2 = x2 - mu, d3 = x3 - mu;
    float v = 0.25f * (d0 * d0 + d1 * d1 + d2 * d2 + d3 * d3);
    float sc = g2[tid] * rsqrtf(v + BEPS);
    float bb = b2[tid];
    out[0 * NOUT + tid] = fmaxf(d0 * sc + bb, 0.f);
    out[1 * NOUT + tid] = fmaxf(d1 * sc + bb, 0.f);
    out[2 * NOUT + tid] = fmaxf(d2 * sc + bb, 0.f);
    out[3 * NOUT + tid] = fmaxf(d3 * sc + bb, 0.f);
  }
}

// ---------------------------------------------------------------------------
extern "C" void kernel_launch(void* const* d_in, const int* in_sizes, int n_in,
                              void* d_out, int out_size, void* d_ws, size_t ws_size,
                              hipStream_t stream) {
  const float* rgb   = (const float*)d_in[0];
  const float* dep   = (const float*)d_in[1];
  const float* Wd    = (const float*)d_in[2];
  const float* Wr    = (const float*)d_in[3];
  const float* Wm1   = (const float*)d_in[4];
  const float* bn1_g = (const float*)d_in[5];
  const float* bn1_b = (const float*)d_in[6];
  const float* Wm2   = (const float*)d_in[7];
  const float* bn2_g = (const float*)d_in[8];
  const float* bn2_b = (const float*)d_in[9];
  float* out = (float*)d_out;

  char* w = (char*)d_ws;
  u16* prF = (u16*)w;             w += (size_t)NB * HW * 192 * 2;   // 6.3 MB frag-order
  u16* pdF = (u16*)w;             w += (size_t)NB * HW * 192 * 2;   // 6.3 MB frag-order
  float* psum  = (float*)w;       w += (size_t)NB * NC * HW * 4;    // 6.3 MB
  float* zpart = (float*)w;       w += (size_t)32 * NB * HW * 4;    // 2 MB
  float* nlz   = (float*)w;       w += (size_t)NB * HW * 4;
  float* spart = (float*)w;       w += (size_t)32 * NB * HW * 4;    // 2 MB
  float* sv    = (float*)w;       w += (size_t)NB * HW * 4;
  float* gap   = (float*)w;       w += (size_t)NB * NC * 4;

  k_prep<<<dim3(HW / 128, NB, 4), 256, 0, stream>>>(rgb, dep, Wr, Wd, psum, prF, pdF);
  k_energy<0><<<dim3(32, 32, NB), 256, 0, stream>>>(prF, pdF, nullptr, zpart);
  k_zred<<<NB * HW / 256, 256, 0, stream>>>(zpart, nlz);
  k_energy<1><<<dim3(32, 32, NB), 256, 0, stream>>>(pdF, prF, nlz, spart);
  k_sred<<<NB * HW / 256, 256, 0, stream>>>(spart, sv);
  k_gap<<<dim3(NC, NB), 256, 0, stream>>>(psum, rgb, dep, sv, gap);
  k_mlp<<<1, 256, 0, stream>>>(gap, Wm1, bn1_g, bn1_b, Wm2, bn2_g, bn2_b, out);
}